// Round 5
// baseline (1627.477 us; speedup 1.0000x reference)
//
#include <hip/hip_runtime.h>
#include <hip/hip_bf16.h>

// GeoMapNet fused forward, MFMA bf16, register-resident fp32 master.
// Block = 256 threads (4 waves) = NB(16) elements = 48 (e,s) rows.
// R5: LDS 38400 B -> 4 blocks/CU (V plane folded into sA rows; X is dead
// after all waves capture xf fragments -- enforced by an in-phase barrier).
// Register diet to fit __launch_bounds__(256,4) (<=128 VGPR, no spills):
// no rolling weight prefetch in QKV/Wo/FFN1 (16 waves/CU TLP hides L2
// latency), streaming attention. fp32 master stays in 192 owner threads.

typedef __attribute__((ext_vector_type(8))) short short8;   // 8 bf16
typedef __attribute__((ext_vector_type(4))) float floatx4;  // MFMA C/D

namespace {
constexpr int S = 3, DIN = 72, D = 100, FF = 512, L = 8, CLS = 40;
constexpr int NB = 16, R = 48, NT = 256;
constexpr int LDA = 136;   // sA row stride (shorts): 16B-aligned, bank-rotated
constexpr int LDH = 264;   // sH row stride (shorts)
constexpr float SCALE = 0.3162277660168379f;  // DH^-0.5

// d_ws element offsets (bf16). Fragment block = 64 lanes x 8 bf16.
constexpr int PL_QKVO = 7 * 4 * 512;                 // per layer
constexpr int WQ_OFF = 0;
constexpr int WK_OFF = WQ_OFF + L * PL_QKVO;
constexpr int WV_OFF = WK_OFF + L * PL_QKVO;
constexpr int WO_OFF = WV_OFF + L * PL_QKVO;
constexpr int PL_W1 = 32 * 4 * 512;
constexpr int W1_OFF = WO_OFF + L * PL_QKVO;
constexpr int PL_W2 = 7 * 16 * 512;
constexpr int W2_OFF = W1_OFF + L * PL_W1;
constexpr int WE_OFF = W2_OFF + L * PL_W2;           // 7 nt x 3 ks
}  // namespace

__device__ __forceinline__ unsigned short f2bf(float f) {  // RTNE (prep only)
  unsigned int u = __float_as_uint(f);
  u = u + 0x7fffu + ((u >> 16) & 1u);
  return (unsigned short)(u >> 16);
}

__device__ __forceinline__ unsigned pkbf(float a, float b) {  // packed cvt
  __hip_bfloat162 h = __float22bfloat162_rn(make_float2(a, b));
  return *reinterpret_cast<unsigned*>(&h);
}

__device__ __forceinline__ void st_bf4(unsigned short* p, floatx4 v) {
  *reinterpret_cast<uint2*>(p) = make_uint2(pkbf(v.x, v.y), pkbf(v.z, v.w));
}

__device__ __forceinline__ void load10(float* o, const unsigned short* p) {
  const unsigned* u = (const unsigned*)p;  // 4B-aligned (even col)
#pragma unroll
  for (int w = 0; w < 5; ++w) {
    unsigned x = u[w];
    o[2 * w] = __uint_as_float(x << 16);
    o[2 * w + 1] = __uint_as_float(x & 0xffff0000u);
  }
}

__device__ __forceinline__ void ldwf4(const unsigned short* base, short8* o) {
#pragma unroll
  for (int ks = 0; ks < 4; ++ks) o[ks] = *(const short8*)(base + ks * 512);
}

// Owner LayerNorm: t = M + scr_row; M = LN(t)*g+b; write bf16 to sA row.
__device__ __forceinline__ void owner_ln(floatx4* M, const float* scrRow,
                                         const float* __restrict__ g,
                                         const float* __restrict__ b,
                                         unsigned short* sARow, int ln_o,
                                         int cnt) {
  floatx4 v[7];
  float sum = 0.f;
#pragma unroll
  for (int i = 0; i < 7; ++i)
    if (i < cnt) {
      const int col = i * 16 + ln_o * 4;
      floatx4 t = M[i] + *(const floatx4*)(scrRow + col);
      v[i] = t;
      sum += t.x + t.y + t.z + t.w;
    }
  sum += __shfl_xor(sum, 1, 4);
  sum += __shfl_xor(sum, 2, 4);
  const float mean = sum * 0.01f;
  float var = 0.f;
#pragma unroll
  for (int i = 0; i < 7; ++i)
    if (i < cnt) {
      floatx4 d = v[i] - mean;
      var += d.x * d.x + d.y * d.y + d.z * d.z + d.w * d.w;
    }
  var += __shfl_xor(var, 1, 4);
  var += __shfl_xor(var, 2, 4);
  const float rstd = rsqrtf(var * 0.01f + 1e-5f);
#pragma unroll
  for (int i = 0; i < 7; ++i)
    if (i < cnt) {
      const int col = i * 16 + ln_o * 4;
      floatx4 o = (v[i] - mean) * rstd * *(const floatx4*)(g + col) +
                  *(const floatx4*)(b + col);
      M[i] = o;
      st_bf4(sARow + col, o);
    }
}

// ------------- weight pre-pack: fp32 row-major -> bf16 fragment blocks -----
__global__ void prep_weights(const float* __restrict__ Wq, const float* __restrict__ Wk,
                             const float* __restrict__ Wv, const float* __restrict__ Wo,
                             const float* __restrict__ W1, const float* __restrict__ W2,
                             const float* __restrict__ We,
                             unsigned short* __restrict__ ws) {
  const int gid = blockIdx.x * 256 + threadIdx.x;
  constexpr int T_QKVO = 8 * 7 * 4 * 64;  // 14336
  constexpr int T_W1 = 8 * 32 * 4 * 64;   // 65536
  constexpr int T_W2 = 8 * 7 * 16 * 64;   // 57344
  constexpr int T_WE = 7 * 3 * 64;        // 1344
  if (gid >= 4 * T_QKVO + T_W1 + T_W2 + T_WE) return;

  const float* src;
  unsigned short* dst;
  int within, ntc, ksc, N, Ksrc, lstride;
  if (gid < 4 * T_QKVO) {
    const int t = gid / T_QKVO;
    within = gid % T_QKVO;
    src = (t == 0 ? Wq : t == 1 ? Wk : t == 2 ? Wv : Wo);
    dst = ws + (t == 0 ? WQ_OFF : t == 1 ? WK_OFF : t == 2 ? WV_OFF : WO_OFF);
    ntc = 7; ksc = 4; N = 100; Ksrc = 100; lstride = 10000;
  } else if (gid < 4 * T_QKVO + T_W1) {
    within = gid - 4 * T_QKVO;
    src = W1; dst = ws + W1_OFF;
    ntc = 32; ksc = 4; N = 512; Ksrc = 100; lstride = 51200;
  } else if (gid < 4 * T_QKVO + T_W1 + T_W2) {
    within = gid - 4 * T_QKVO - T_W1;
    src = W2; dst = ws + W2_OFF;
    ntc = 7; ksc = 16; N = 100; Ksrc = 512; lstride = 51200;
  } else {
    within = gid - 4 * T_QKVO - T_W1 - T_W2;
    src = We; dst = ws + WE_OFF;
    ntc = 7; ksc = 3; N = 100; Ksrc = 72; lstride = 0;
  }
  const int lane = within & 63;
  int tmp = within >> 6;
  const int ks = tmp % ksc; tmp /= ksc;
  const int nt = tmp % ntc;
  const int lay = tmp / ntc;
  const int n = nt * 16 + (lane & 15);
  const int kb = ks * 32 + (lane >> 4) * 8;
  const float* sp = src + (size_t)lay * lstride + (size_t)n * Ksrc;
  unsigned short o[8];
#pragma unroll
  for (int j = 0; j < 8; ++j) {
    const int k = kb + j;
    float v = (n < N && k < Ksrc) ? sp[k] : 0.f;
    o[j] = f2bf(v);
  }
  uint4 pk = make_uint4((unsigned)o[0] | ((unsigned)o[1] << 16),
                        (unsigned)o[2] | ((unsigned)o[3] << 16),
                        (unsigned)o[4] | ((unsigned)o[5] << 16),
                        (unsigned)o[6] | ((unsigned)o[7] << 16));
  *reinterpret_cast<uint4*>(dst + (size_t)within * 8) = pk;
}

__global__ __launch_bounds__(NT, 4)
void geomap_mfma(const float* __restrict__ gx,
                 const float* __restrict__ be, const float* __restrict__ pe,
                 const float* __restrict__ bq, const float* __restrict__ bk,
                 const float* __restrict__ bv, const float* __restrict__ bo,
                 const float* __restrict__ g1, const float* __restrict__ bt1,
                 const float* __restrict__ b1, const float* __restrict__ b2,
                 const float* __restrict__ g2, const float* __restrict__ bt2,
                 const float* __restrict__ Wf, const float* __restrict__ bfc,
                 const unsigned short* __restrict__ ws,
                 float* __restrict__ gout) {
  // 38400 B total -> 4 blocks/CU (4*38400 = 153600 <= 163840)
  __shared__ __align__(16) char smem[38400];
  unsigned short* sA = (unsigned short*)smem;            // [48][136]: X|V|ctx
  unsigned short* sQ = (unsigned short*)(smem + 13056);  // [48][100] bf16
  unsigned short* sK = (unsigned short*)(smem + 22656);  // [48][100]
  unsigned short* sH = (unsigned short*)(smem + 13056);  // [48][264] (alias)
  float* scr = (float*)(smem + 13056);                   // [48][100] (alias)

  const int tid = threadIdx.x;
  const int lane = tid & 63;
  const int wid = tid >> 6;
  const int l15 = lane & 15;
  const int quad = lane >> 4;
  const int blk = blockIdx.x;

  const bool owner = tid < 192;
  const int row_o = tid >> 2, ln_o = tid & 3;
  const int cnt_o = (ln_o == 0) ? 7 : 6;
  floatx4 M[7];  // fp32 master: 25 values per owner thread

  // ---- zero sA (pad cols stay 0 forever), then stage x as bf16 ----
  for (int i = tid; i < R * LDA / 2; i += NT) ((unsigned*)sA)[i] = 0u;
  __syncthreads();
  for (int i = tid; i < R * DIN / 2; i += NT) {
    const int row = i / 36, c = (i % 36) * 2;
    const float2 f2 = *(const float2*)(gx + ((size_t)blk * R + row) * DIN + c);
    ((unsigned*)sA)[row * (LDA / 2) + (c >> 1)] = pkbf(f2.x, f2.y);
  }
  __syncthreads();

  // ---- embedding via MFMA: X = x @ We^T + be + pe ----
  {
    short8 xe[3][3];
#pragma unroll
    for (int mt = 0; mt < 3; ++mt)
#pragma unroll
      for (int ks = 0; ks < 3; ++ks)
        xe[mt][ks] = *(const short8*)(sA + (mt * 16 + l15) * LDA + ks * 32 + quad * 8);
    __syncthreads();  // all x-frags in regs before epilogue overwrites sA
    for (int nt = wid; nt < 7; nt += 4) {
      const unsigned short* wb = ws + WE_OFF + (size_t)(nt * 3) * 512 + (size_t)lane * 8;
      short8 w0 = *(const short8*)(wb);
      short8 w1 = *(const short8*)(wb + 512);
      short8 w2 = *(const short8*)(wb + 1024);
      const int n0 = nt * 16 + quad * 4;
      floatx4 a[3];
#pragma unroll
      for (int mt = 0; mt < 3; ++mt) {
        a[mt] = floatx4{0.f, 0.f, 0.f, 0.f};
        a[mt] = __builtin_amdgcn_mfma_f32_16x16x32_bf16(w0, xe[mt][0], a[mt], 0, 0, 0);
        a[mt] = __builtin_amdgcn_mfma_f32_16x16x32_bf16(w1, xe[mt][1], a[mt], 0, 0, 0);
        a[mt] = __builtin_amdgcn_mfma_f32_16x16x32_bf16(w2, xe[mt][2], a[mt], 0, 0, 0);
      }
      if (n0 < D) {
        const floatx4 bev = *(const floatx4*)(be + n0);
#pragma unroll
        for (int mt = 0; mt < 3; ++mt) {
          const int row = mt * 16 + l15;
          const int s = row % 3;
          const floatx4 pev = *(const floatx4*)(pe + s * D + n0);
          const floatx4 o = a[mt] + bev + pev;
          *(floatx4*)(scr + row * D + n0) = o;
          st_bf4(sA + row * LDA + n0, o);
        }
      }
    }
  }
  __syncthreads();
  if (owner) {
#pragma unroll
    for (int i = 0; i < 7; ++i)
      if (i < cnt_o) M[i] = *(const floatx4*)(scr + row_o * D + i * 16 + ln_o * 4);
  }
  __syncthreads();  // scratch free before QKV epilogue writes

  for (int lay = 0; lay < L; ++lay) {
    // ---- QKV: 21 units; V lands in sA rows (X dead after xf capture) ----
    {
      short8 xf[3][4];
#pragma unroll
      for (int mt = 0; mt < 3; ++mt)
#pragma unroll
        for (int ks = 0; ks < 4; ++ks)
          xf[mt][ks] = *(const short8*)(sA + (mt * 16 + l15) * LDA + ks * 32 + quad * 8);
      __syncthreads();  // every wave has X frags; V may overwrite sA now
      const unsigned short* wbase[3] = {ws + WQ_OFF + lay * PL_QKVO,
                                        ws + WK_OFF + lay * PL_QKVO,
                                        ws + WV_OFF + lay * PL_QKVO};
      for (int u = wid; u < 21; u += 4) {
        const int mat = u / 7, nt = u % 7;
        short8 wf[4];
        ldwf4(wbase[mat] + (size_t)nt * 2048 + (size_t)lane * 8, wf);
        const int n0 = nt * 16 + quad * 4;
        floatx4 bias = {0.f, 0.f, 0.f, 0.f};
        const float* bsrc = (mat == 0 ? bq : mat == 1 ? bk : bv) + lay * D;
        if (n0 < D) bias = *(const floatx4*)(bsrc + n0);
        floatx4 a0 = bias, a1 = bias, a2 = bias;
#pragma unroll
        for (int ks = 0; ks < 4; ++ks) {
          a0 = __builtin_amdgcn_mfma_f32_16x16x32_bf16(wf[ks], xf[0][ks], a0, 0, 0, 0);
          a1 = __builtin_amdgcn_mfma_f32_16x16x32_bf16(wf[ks], xf[1][ks], a1, 0, 0, 0);
          a2 = __builtin_amdgcn_mfma_f32_16x16x32_bf16(wf[ks], xf[2][ks], a2, 0, 0, 0);
        }
        if (n0 < D) {
          const floatx4 av[3] = {a0, a1, a2};
#pragma unroll
          for (int mt = 0; mt < 3; ++mt) {
            const int row = mt * 16 + l15;
            if (mat == 0) st_bf4(sQ + row * 100 + n0, av[mt]);
            else if (mat == 1) st_bf4(sK + row * 100 + n0, av[mt]);
            else st_bf4(sA + row * LDA + n0, av[mt]);  // V into sA
          }
        }
      }
    }
    __syncthreads();

    // ---- attention: 160 jobs = (e,h); V read from sA, ctx written in-place
    // (per-thread slices disjoint; V preloaded before ctx stores) ----
    if (tid < 160) {
      const int e = tid / 10, h = tid % 10;
      const unsigned short* Qe = sQ + e * 300;  // stride-100 rows -> flat 300
      const unsigned short* Ke = sK + e * 300;
      float Kv[3][10];
#pragma unroll
      for (int t = 0; t < 3; ++t) load10(Kv[t], Ke + h * 30 + t * 10);
      float p[3][3];
#pragma unroll
      for (int sq = 0; sq < 3; ++sq) {
        float q[10];
        load10(q, Qe + h * 30 + sq * 10);
        float sc[3];
#pragma unroll
        for (int t = 0; t < 3; ++t) {
          float s0 = 0.f;
#pragma unroll
          for (int j = 0; j < 10; ++j) s0 += q[j] * Kv[t][j];
          sc[t] = s0 * SCALE;
        }
        const float m = fmaxf(sc[0], fmaxf(sc[1], sc[2]));
        float p0 = __expf(sc[0] - m), p1 = __expf(sc[1] - m), p2 = __expf(sc[2] - m);
        const float inv = 1.f / (p0 + p1 + p2);
        p[sq][0] = p0 * inv; p[sq][1] = p1 * inv; p[sq][2] = p2 * inv;
      }
      float ctx[3][10];
#pragma unroll
      for (int sq = 0; sq < 3; ++sq)
#pragma unroll
        for (int j = 0; j < 10; ++j) ctx[sq][j] = 0.f;
#pragma unroll
      for (int t = 0; t < 3; ++t) {
        const int pv = h * 30 + t * 10;
        float vv[10];
        load10(vv, sA + (e * 3 + pv / 100) * LDA + (pv % 100));
#pragma unroll
        for (int sq = 0; sq < 3; ++sq)
#pragma unroll
          for (int j = 0; j < 10; ++j) ctx[sq][j] += p[sq][t] * vv[j];
      }
#pragma unroll
      for (int sq = 0; sq < 3; ++sq) {
        const int pq = h * 30 + sq * 10;
        unsigned* dp = (unsigned*)(sA + (e * 3 + pq / 100) * LDA + (pq % 100));
#pragma unroll
        for (int w = 0; w < 5; ++w)
          dp[w] = pkbf(ctx[sq][2 * w], ctx[sq][2 * w + 1]);
      }
    }
    __syncthreads();

    // ---- Wo -> scratch (no residual; owners add M at LN1) ----
    {
      short8 cf[3][4];
#pragma unroll
      for (int mt = 0; mt < 3; ++mt)
#pragma unroll
        for (int ks = 0; ks < 4; ++ks)
          cf[mt][ks] = *(const short8*)(sA + (mt * 16 + l15) * LDA + ks * 32 + quad * 8);
      const unsigned short* wbase = ws + WO_OFF + lay * PL_QKVO;
      for (int u = wid; u < 7; u += 4) {
        short8 wf[4];
        ldwf4(wbase + (size_t)u * 2048 + (size_t)lane * 8, wf);
        const int n0 = u * 16 + quad * 4;
        floatx4 bias = {0.f, 0.f, 0.f, 0.f};
        if (n0 < D) bias = *(const floatx4*)(bo + lay * D + n0);
        floatx4 a0 = bias, a1 = bias, a2 = bias;
#pragma unroll
        for (int ks = 0; ks < 4; ++ks) {
          a0 = __builtin_amdgcn_mfma_f32_16x16x32_bf16(wf[ks], cf[0][ks], a0, 0, 0, 0);
          a1 = __builtin_amdgcn_mfma_f32_16x16x32_bf16(wf[ks], cf[1][ks], a1, 0, 0, 0);
          a2 = __builtin_amdgcn_mfma_f32_16x16x32_bf16(wf[ks], cf[2][ks], a2, 0, 0, 0);
        }
        if (n0 < D) {
          const floatx4 av[3] = {a0, a1, a2};
#pragma unroll
          for (int mt = 0; mt < 3; ++mt)
            *(floatx4*)(scr + (mt * 16 + l15) * D + n0) = av[mt];
        }
      }
    }
    __syncthreads();
    if (owner)
      owner_ln(M, scr + row_o * D, g1 + lay * D, bt1 + lay * D,
               sA + row_o * LDA, ln_o, cnt_o);
    __syncthreads();

    // ---- FFN: 2 chunks of 256 hidden; FFN2 acc persistent in VGPRs ----
    {
      short8 ff[3][4];
#pragma unroll
      for (int mt = 0; mt < 3; ++mt)
#pragma unroll
        for (int ks = 0; ks < 4; ++ks)
          ff[mt][ks] = *(const short8*)(sA + (mt * 16 + l15) * LDA + ks * 32 + quad * 8);
      floatx4 facc[2][3];
#pragma unroll
      for (int idx = 0; idx < 2; ++idx) {
        const int nt = wid + 4 * idx;
        const int n0 = nt * 16 + quad * 4;
        floatx4 bias = {0.f, 0.f, 0.f, 0.f};
        if (nt < 7 && n0 < D) bias = *(const floatx4*)(b2 + lay * D + n0);
#pragma unroll
        for (int mt = 0; mt < 3; ++mt) facc[idx][mt] = bias;
      }
      const unsigned short* w1b = ws + W1_OFF + (size_t)lay * PL_W1;
      const unsigned short* w2b = ws + W2_OFF + (size_t)lay * PL_W2;
      const int nts1 = wid + 4;  // second FFN2 nt (valid if < 7)

      for (int c = 0; c < 2; ++c) {
        // FFN1: 4 units per wave
#pragma unroll
        for (int k = 0; k < 4; ++k) {
          const int ntg = c * 16 + wid + 4 * k;
          short8 wf[4];
          ldwf4(w1b + (size_t)ntg * 2048 + (size_t)lane * 8, wf);
          const floatx4 b1v = *(const floatx4*)(b1 + lay * FF + ntg * 16 + quad * 4);
          floatx4 a0 = b1v, a1 = b1v, a2 = b1v;
#pragma unroll
          for (int ks = 0; ks < 4; ++ks) {
            a0 = __builtin_amdgcn_mfma_f32_16x16x32_bf16(wf[ks], ff[0][ks], a0, 0, 0, 0);
            a1 = __builtin_amdgcn_mfma_f32_16x16x32_bf16(wf[ks], ff[1][ks], a1, 0, 0, 0);
            a2 = __builtin_amdgcn_mfma_f32_16x16x32_bf16(wf[ks], ff[2][ks], a2, 0, 0, 0);
          }
          const int nloc = (wid + 4 * k) * 16 + quad * 4;
          const floatx4 av[3] = {a0, a1, a2};
#pragma unroll
          for (int mt = 0; mt < 3; ++mt) {
            const int row = mt * 16 + l15;
            floatx4 r;
            r.x = fmaxf(av[mt].x, 0.f); r.y = fmaxf(av[mt].y, 0.f);
            r.z = fmaxf(av[mt].z, 0.f); r.w = fmaxf(av[mt].w, 0.f);
            st_bf4(sH + row * LDH + nloc, r);
          }
        }
        __syncthreads();
        // FFN2: shared hf across the wave's 1-2 nt units, wf pair prefetch
        short8 wA = *(const short8*)(w2b + (size_t)(wid * 16 + c * 8) * 512 + (size_t)lane * 8);
        short8 wB = wA;
        if (nts1 < 7)
          wB = *(const short8*)(w2b + (size_t)(nts1 * 16 + c * 8) * 512 + (size_t)lane * 8);
#pragma unroll
        for (int ksl = 0; ksl < 8; ++ksl) {
          short8 nA = wA, nB = wB;
          if (ksl < 7) {
            nA = *(const short8*)(w2b + (size_t)(wid * 16 + c * 8 + ksl + 1) * 512 + (size_t)lane * 8);
            if (nts1 < 7)
              nB = *(const short8*)(w2b + (size_t)(nts1 * 16 + c * 8 + ksl + 1) * 512 + (size_t)lane * 8);
          }
          short8 hf[3];
#pragma unroll
          for (int mt = 0; mt < 3; ++mt)
            hf[mt] = *(const short8*)(sH + (mt * 16 + l15) * LDH + ksl * 32 + quad * 8);
#pragma unroll
          for (int mt = 0; mt < 3; ++mt)
            facc[0][mt] = __builtin_amdgcn_mfma_f32_16x16x32_bf16(wA, hf[mt], facc[0][mt], 0, 0, 0);
          if (nts1 < 7) {
#pragma unroll
            for (int mt = 0; mt < 3; ++mt)
              facc[1][mt] = __builtin_amdgcn_mfma_f32_16x16x32_bf16(wB, hf[mt], facc[1][mt], 0, 0, 0);
          }
          wA = nA; wB = nB;
        }
        __syncthreads();  // sH consumed (next FFN1 write / scr write safe)
      }
      // FFN2 epilogue -> scratch
#pragma unroll
      for (int idx = 0; idx < 2; ++idx) {
        const int nt = wid + 4 * idx;
        const int n0 = nt * 16 + quad * 4;
        if (nt < 7 && n0 < D) {
#pragma unroll
          for (int mt = 0; mt < 3; ++mt)
            *(floatx4*)(scr + (mt * 16 + l15) * D + n0) = facc[idx][mt];
        }
      }
    }
    __syncthreads();
    if (owner)
      owner_ln(M, scr + row_o * D, g2 + lay * D, bt2 + lay * D,
               sA + row_o * LDA, ln_o, cnt_o);
    __syncthreads();
  }

  // ---- dump master -> scratch, then classifier (fp32 VALU, exact) ----
  if (owner) {
#pragma unroll
    for (int i = 0; i < 7; ++i)
      if (i < cnt_o)
        *(floatx4*)(scr + row_o * D + i * 16 + ln_o * 4) = M[i];
  }
  __syncthreads();
  if (tid < 160) {
    const int c = tid % 40, eg = tid / 40;
    float acc[4];
#pragma unroll
    for (int i = 0; i < 4; ++i) acc[i] = bfc[c];
    const floatx4* wr = (const floatx4*)(Wf + c * 300);
    for (int kq = 0; kq < 75; ++kq) {
      const floatx4 w4 = wr[kq];
#pragma unroll
      for (int i = 0; i < 4; ++i) {
        const floatx4 x4 = *(const floatx4*)(scr + (eg * 4 + i) * 300 + kq * 4);
        acc[i] += w4.x * x4.x + w4.y * x4.y + w4.z * x4.z + w4.w * x4.w;
      }
    }
#pragma unroll
    for (int i = 0; i < 4; ++i)
      gout[((size_t)blk * NB + eg * 4 + i) * CLS + c] = acc[i];
  }
}

extern "C" void kernel_launch(void* const* d_in, const int* in_sizes, int n_in,
                              void* d_out, int out_size, void* d_ws,
                              size_t ws_size, hipStream_t stream) {
  const float* x   = (const float*)d_in[0];
  const float* We  = (const float*)d_in[3];
  const float* be  = (const float*)d_in[4];
  const float* pe  = (const float*)d_in[5];
  const float* Wq  = (const float*)d_in[6];
  const float* bq  = (const float*)d_in[7];
  const float* Wk  = (const float*)d_in[8];
  const float* bk  = (const float*)d_in[9];
  const float* Wv  = (const float*)d_in[10];
  const float* bv  = (const float*)d_in[11];
  const float* Wo  = (const float*)d_in[12];
  const float* bo  = (const float*)d_in[13];
  const float* g1  = (const float*)d_in[14];
  const float* bt1 = (const float*)d_in[15];
  const float* W1  = (const float*)d_in[16];
  const float* b1  = (const float*)d_in[17];
  const float* W2  = (const float*)d_in[18];
  const float* b2  = (const float*)d_in[19];
  const float* g2  = (const float*)d_in[20];
  const float* bt2 = (const float*)d_in[21];
  const float* Wf  = (const float*)d_in[22];
  const float* bf  = (const float*)d_in[23];
  float* out = (float*)d_out;
  unsigned short* ws = (unsigned short*)d_ws;

  prep_weights<<<710, 256, 0, stream>>>(Wq, Wk, Wv, Wo, W1, W2, We, ws);

  const int B = in_sizes[0] / (S * DIN);
  const int blocks = B / NB;  // 4096
  geomap_mfma<<<blocks, 256, 0, stream>>>(x, be, pe, bq, bk, bv, bo,
                                          g1, bt1, b1, b2, g2, bt2, Wf, bf,
                                          ws, out);
}

// Round 6
// 1369.841 us; speedup vs baseline: 1.1881x; 1.1881x over previous
//
#include <hip/hip_runtime.h>
#include <hip/hip_bf16.h>

// GeoMapNet fused forward, MFMA bf16, LDS-resident fp32 master (R6).
// Block = 256 threads (4 waves) = NB(16) elements = 48 (e,s) rows.
// LDS 51456 B -> 3 blocks/CU. Persistent planes: sA (bf16 X/V/ctx, 13056 B)
// + sXf (fp32 master, 19200 B). One 19200-B region time-shares
// {sQ+sK} -> {scr fp32 pre-LN} -> {sH FFN hidden (3 chunks 192/192/128)}.
// No long-lived registers across barriers => no scratch spills (R4/R5 lesson:
// a register master live across 13 barriers/layer always spills).

typedef __attribute__((ext_vector_type(8))) short short8;   // 8 bf16
typedef __attribute__((ext_vector_type(4))) float floatx4;  // MFMA C/D

namespace {
constexpr int S = 3, DIN = 72, D = 100, FF = 512, L = 8, CLS = 40;
constexpr int NB = 16, R = 48, NT = 256;
constexpr int LDA = 136;   // sA row stride (shorts): 16B-aligned, bank-rotated
constexpr int LDH = 200;   // sH row stride (shorts): 400 B, rotate 4 banks
constexpr float SCALE = 0.3162277660168379f;  // DH^-0.5

// d_ws element offsets (bf16). Fragment block = 64 lanes x 8 bf16.
constexpr int PL_QKVO = 7 * 4 * 512;                 // per layer
constexpr int WQ_OFF = 0;
constexpr int WK_OFF = WQ_OFF + L * PL_QKVO;
constexpr int WV_OFF = WK_OFF + L * PL_QKVO;
constexpr int WO_OFF = WV_OFF + L * PL_QKVO;
constexpr int PL_W1 = 32 * 4 * 512;
constexpr int W1_OFF = WO_OFF + L * PL_QKVO;
constexpr int PL_W2 = 7 * 16 * 512;
constexpr int W2_OFF = W1_OFF + L * PL_W1;
constexpr int WE_OFF = W2_OFF + L * PL_W2;           // 7 nt x 3 ks
}  // namespace

__device__ __forceinline__ unsigned short f2bf(float f) {  // RTNE (prep only)
  unsigned int u = __float_as_uint(f);
  u = u + 0x7fffu + ((u >> 16) & 1u);
  return (unsigned short)(u >> 16);
}

__device__ __forceinline__ unsigned pkbf(float a, float b) {  // packed cvt
  __hip_bfloat162 h = __float22bfloat162_rn(make_float2(a, b));
  return *reinterpret_cast<unsigned*>(&h);
}

__device__ __forceinline__ void st_bf4(unsigned short* p, floatx4 v) {
  *reinterpret_cast<uint2*>(p) = make_uint2(pkbf(v.x, v.y), pkbf(v.z, v.w));
}

__device__ __forceinline__ void load10(float* o, const unsigned short* p) {
  const unsigned* u = (const unsigned*)p;  // 4B-aligned (even col)
#pragma unroll
  for (int w = 0; w < 5; ++w) {
    unsigned x = u[w];
    o[2 * w] = __uint_as_float(x << 16);
    o[2 * w + 1] = __uint_as_float(x & 0xffff0000u);
  }
}

__device__ __forceinline__ void ldwf4(const unsigned short* base, short8* o) {
#pragma unroll
  for (int ks = 0; ks < 4; ++ks) o[ks] = *(const short8*)(base + ks * 512);
}

// LayerNorm over 48 rows of 100; 4 lanes/row (192 threads), vectorized.
// t = xrow + srow (residual); xrow = LN(t)*g+b (fp32 master, in-place safe:
// values cached in regs); also writes bf16 to the sA row.
__device__ __forceinline__ void ln_rows(float* xrow, const float* srow,
                                        const float* __restrict__ g,
                                        const float* __restrict__ b,
                                        unsigned short* sArow, int ln,
                                        int cnt) {
  floatx4 v[7];
  float sum = 0.f;
#pragma unroll
  for (int i = 0; i < 7; ++i)
    if (i < cnt) {
      const int col = i * 16 + ln * 4;
      floatx4 t = *(const floatx4*)(xrow + col) + *(const floatx4*)(srow + col);
      v[i] = t;
      sum += t.x + t.y + t.z + t.w;
    }
  sum += __shfl_xor(sum, 1, 4);
  sum += __shfl_xor(sum, 2, 4);
  const float mean = sum * 0.01f;
  float var = 0.f;
#pragma unroll
  for (int i = 0; i < 7; ++i)
    if (i < cnt) {
      floatx4 d = v[i] - mean;
      var += d.x * d.x + d.y * d.y + d.z * d.z + d.w * d.w;
    }
  var += __shfl_xor(var, 1, 4);
  var += __shfl_xor(var, 2, 4);
  const float rstd = rsqrtf(var * 0.01f + 1e-5f);
#pragma unroll
  for (int i = 0; i < 7; ++i)
    if (i < cnt) {
      const int col = i * 16 + ln * 4;
      floatx4 o = (v[i] - mean) * rstd * *(const floatx4*)(g + col) +
                  *(const floatx4*)(b + col);
      *(floatx4*)(xrow + col) = o;
      st_bf4(sArow + col, o);
    }
}

// ------------- weight pre-pack: fp32 row-major -> bf16 fragment blocks -----
__global__ void prep_weights(const float* __restrict__ Wq, const float* __restrict__ Wk,
                             const float* __restrict__ Wv, const float* __restrict__ Wo,
                             const float* __restrict__ W1, const float* __restrict__ W2,
                             const float* __restrict__ We,
                             unsigned short* __restrict__ ws) {
  const int gid = blockIdx.x * 256 + threadIdx.x;
  constexpr int T_QKVO = 8 * 7 * 4 * 64;  // 14336
  constexpr int T_W1 = 8 * 32 * 4 * 64;   // 65536
  constexpr int T_W2 = 8 * 7 * 16 * 64;   // 57344
  constexpr int T_WE = 7 * 3 * 64;        // 1344
  if (gid >= 4 * T_QKVO + T_W1 + T_W2 + T_WE) return;

  const float* src;
  unsigned short* dst;
  int within, ntc, ksc, N, Ksrc, lstride;
  if (gid < 4 * T_QKVO) {
    const int t = gid / T_QKVO;
    within = gid % T_QKVO;
    src = (t == 0 ? Wq : t == 1 ? Wk : t == 2 ? Wv : Wo);
    dst = ws + (t == 0 ? WQ_OFF : t == 1 ? WK_OFF : t == 2 ? WV_OFF : WO_OFF);
    ntc = 7; ksc = 4; N = 100; Ksrc = 100; lstride = 10000;
  } else if (gid < 4 * T_QKVO + T_W1) {
    within = gid - 4 * T_QKVO;
    src = W1; dst = ws + W1_OFF;
    ntc = 32; ksc = 4; N = 512; Ksrc = 100; lstride = 51200;
  } else if (gid < 4 * T_QKVO + T_W1 + T_W2) {
    within = gid - 4 * T_QKVO - T_W1;
    src = W2; dst = ws + W2_OFF;
    ntc = 7; ksc = 16; N = 100; Ksrc = 512; lstride = 51200;
  } else {
    within = gid - 4 * T_QKVO - T_W1 - T_W2;
    src = We; dst = ws + WE_OFF;
    ntc = 7; ksc = 3; N = 100; Ksrc = 72; lstride = 0;
  }
  const int lane = within & 63;
  int tmp = within >> 6;
  const int ks = tmp % ksc; tmp /= ksc;
  const int nt = tmp % ntc;
  const int lay = tmp / ntc;
  const int n = nt * 16 + (lane & 15);
  const int kb = ks * 32 + (lane >> 4) * 8;
  const float* sp = src + (size_t)lay * lstride + (size_t)n * Ksrc;
  unsigned short o[8];
#pragma unroll
  for (int j = 0; j < 8; ++j) {
    const int k = kb + j;
    float v = (n < N && k < Ksrc) ? sp[k] : 0.f;
    o[j] = f2bf(v);
  }
  uint4 pk = make_uint4((unsigned)o[0] | ((unsigned)o[1] << 16),
                        (unsigned)o[2] | ((unsigned)o[3] << 16),
                        (unsigned)o[4] | ((unsigned)o[5] << 16),
                        (unsigned)o[6] | ((unsigned)o[7] << 16));
  *reinterpret_cast<uint4*>(dst + (size_t)within * 8) = pk;
}

__global__ __launch_bounds__(NT, 3)
void geomap_mfma(const float* __restrict__ gx,
                 const float* __restrict__ be, const float* __restrict__ pe,
                 const float* __restrict__ bq, const float* __restrict__ bk,
                 const float* __restrict__ bv, const float* __restrict__ bo,
                 const float* __restrict__ g1, const float* __restrict__ bt1,
                 const float* __restrict__ b1, const float* __restrict__ b2,
                 const float* __restrict__ g2, const float* __restrict__ bt2,
                 const float* __restrict__ Wf, const float* __restrict__ bfc,
                 const unsigned short* __restrict__ ws,
                 float* __restrict__ gout) {
  // 51456 B -> 3 blocks/CU (3*51456 = 154368 <= 163840)
  __shared__ __align__(16) char smem[51456];
  unsigned short* sA = (unsigned short*)smem;            // [48][136]: X|V|ctx
  float* sXf = (float*)(smem + 13056);                   // [48][100] fp32 master
  unsigned short* sQ = (unsigned short*)(smem + 32256);  // [48][100] bf16
  unsigned short* sK = (unsigned short*)(smem + 41856);  // [48][100]
  float* scr = (float*)(smem + 32256);                   // [48][100] (alias C)
  unsigned short* sH = (unsigned short*)(smem + 32256);  // [48][200] (alias C)

  const int tid = threadIdx.x;
  const int lane = tid & 63;
  const int wid = tid >> 6;
  const int l15 = lane & 15;
  const int quad = lane >> 4;
  const int blk = blockIdx.x;

  const int row_o = tid >> 2, ln_o = tid & 3;  // LN job (threads < 192)
  const int cnt_o = (ln_o == 0) ? 7 : 6;

  // ---- zero sA (pad cols stay 0 forever), then stage x as bf16 ----
  for (int i = tid; i < R * LDA / 2; i += NT) ((unsigned*)sA)[i] = 0u;
  __syncthreads();
  for (int i = tid; i < R * DIN / 2; i += NT) {
    const int row = i / 36, c = (i % 36) * 2;
    const float2 f2 = *(const float2*)(gx + ((size_t)blk * R + row) * DIN + c);
    ((unsigned*)sA)[row * (LDA / 2) + (c >> 1)] = pkbf(f2.x, f2.y);
  }
  __syncthreads();

  // ---- embedding via MFMA: sXf/sA = x @ We^T + be + pe ----
  {
    short8 xe[3][3];
#pragma unroll
    for (int mt = 0; mt < 3; ++mt)
#pragma unroll
      for (int ks = 0; ks < 3; ++ks)
        xe[mt][ks] = *(const short8*)(sA + (mt * 16 + l15) * LDA + ks * 32 + quad * 8);
    __syncthreads();  // all x-frags in regs before epilogue overwrites sA
    for (int nt = wid; nt < 7; nt += 4) {
      const unsigned short* wb = ws + WE_OFF + (size_t)(nt * 3) * 512 + (size_t)lane * 8;
      short8 w0 = *(const short8*)(wb);
      short8 w1 = *(const short8*)(wb + 512);
      short8 w2 = *(const short8*)(wb + 1024);
      const int n0 = nt * 16 + quad * 4;
      floatx4 a[3];
#pragma unroll
      for (int mt = 0; mt < 3; ++mt) {
        a[mt] = floatx4{0.f, 0.f, 0.f, 0.f};
        a[mt] = __builtin_amdgcn_mfma_f32_16x16x32_bf16(w0, xe[mt][0], a[mt], 0, 0, 0);
        a[mt] = __builtin_amdgcn_mfma_f32_16x16x32_bf16(w1, xe[mt][1], a[mt], 0, 0, 0);
        a[mt] = __builtin_amdgcn_mfma_f32_16x16x32_bf16(w2, xe[mt][2], a[mt], 0, 0, 0);
      }
      if (n0 < D) {
        const floatx4 bev = *(const floatx4*)(be + n0);
#pragma unroll
        for (int mt = 0; mt < 3; ++mt) {
          const int row = mt * 16 + l15;
          const int s = row % 3;
          const floatx4 pev = *(const floatx4*)(pe + s * D + n0);
          const floatx4 o = a[mt] + bev + pev;
          *(floatx4*)(sXf + row * D + n0) = o;
          st_bf4(sA + row * LDA + n0, o);
        }
      }
    }
  }
  __syncthreads();

  for (int lay = 0; lay < L; ++lay) {
    // ---- QKV: 21 units; V lands in sA rows (X dead after xf capture) ----
    {
      short8 xf[3][4];
#pragma unroll
      for (int mt = 0; mt < 3; ++mt)
#pragma unroll
        for (int ks = 0; ks < 4; ++ks)
          xf[mt][ks] = *(const short8*)(sA + (mt * 16 + l15) * LDA + ks * 32 + quad * 8);
      __syncthreads();  // every wave has X frags; V may overwrite sA now
      const unsigned short* wbase[3] = {ws + WQ_OFF + lay * PL_QKVO,
                                        ws + WK_OFF + lay * PL_QKVO,
                                        ws + WV_OFF + lay * PL_QKVO};
      for (int u = wid; u < 21; u += 4) {
        const int mat = u / 7, nt = u % 7;
        short8 wf[4];
        ldwf4(wbase[mat] + (size_t)nt * 2048 + (size_t)lane * 8, wf);
        const int n0 = nt * 16 + quad * 4;
        floatx4 bias = {0.f, 0.f, 0.f, 0.f};
        const float* bsrc = (mat == 0 ? bq : mat == 1 ? bk : bv) + lay * D;
        if (n0 < D) bias = *(const floatx4*)(bsrc + n0);
        floatx4 a0 = bias, a1 = bias, a2 = bias;
#pragma unroll
        for (int ks = 0; ks < 4; ++ks) {
          a0 = __builtin_amdgcn_mfma_f32_16x16x32_bf16(wf[ks], xf[0][ks], a0, 0, 0, 0);
          a1 = __builtin_amdgcn_mfma_f32_16x16x32_bf16(wf[ks], xf[1][ks], a1, 0, 0, 0);
          a2 = __builtin_amdgcn_mfma_f32_16x16x32_bf16(wf[ks], xf[2][ks], a2, 0, 0, 0);
        }
        if (n0 < D) {
          const floatx4 av[3] = {a0, a1, a2};
#pragma unroll
          for (int mt = 0; mt < 3; ++mt) {
            const int row = mt * 16 + l15;
            if (mat == 0) st_bf4(sQ + row * 100 + n0, av[mt]);
            else if (mat == 1) st_bf4(sK + row * 100 + n0, av[mt]);
            else st_bf4(sA + row * LDA + n0, av[mt]);  // V into sA
          }
        }
      }
    }
    __syncthreads();

    // ---- attention: 160 jobs = (e,h); V in sA, ctx written in-place ----
    if (tid < 160) {
      const int e = tid / 10, h = tid % 10;
      const unsigned short* Qe = sQ + e * 300;  // stride-100 rows -> flat 300
      const unsigned short* Ke = sK + e * 300;
      float Kv[3][10];
#pragma unroll
      for (int t = 0; t < 3; ++t) load10(Kv[t], Ke + h * 30 + t * 10);
      float p[3][3];
#pragma unroll
      for (int sq = 0; sq < 3; ++sq) {
        float q[10];
        load10(q, Qe + h * 30 + sq * 10);
        float sc[3];
#pragma unroll
        for (int t = 0; t < 3; ++t) {
          float s0 = 0.f;
#pragma unroll
          for (int j = 0; j < 10; ++j) s0 += q[j] * Kv[t][j];
          sc[t] = s0 * SCALE;
        }
        const float m = fmaxf(sc[0], fmaxf(sc[1], sc[2]));
        float p0 = __expf(sc[0] - m), p1 = __expf(sc[1] - m), p2 = __expf(sc[2] - m);
        const float inv = 1.f / (p0 + p1 + p2);
        p[sq][0] = p0 * inv; p[sq][1] = p1 * inv; p[sq][2] = p2 * inv;
      }
      float ctx[3][10];
#pragma unroll
      for (int sq = 0; sq < 3; ++sq)
#pragma unroll
        for (int j = 0; j < 10; ++j) ctx[sq][j] = 0.f;
#pragma unroll
      for (int t = 0; t < 3; ++t) {
        const int pv = h * 30 + t * 10;
        float vv[10];
        load10(vv, sA + (e * 3 + pv / 100) * LDA + (pv % 100));
#pragma unroll
        for (int sq = 0; sq < 3; ++sq)
#pragma unroll
          for (int j = 0; j < 10; ++j) ctx[sq][j] += p[sq][t] * vv[j];
      }
#pragma unroll
      for (int sq = 0; sq < 3; ++sq) {
        const int pq = h * 30 + sq * 10;
        unsigned* dp = (unsigned*)(sA + (e * 3 + pq / 100) * LDA + (pq % 100));
#pragma unroll
        for (int w = 0; w < 5; ++w)
          dp[w] = pkbf(ctx[sq][2 * w], ctx[sq][2 * w + 1]);
      }
    }
    __syncthreads();

    // ---- Wo -> scr (overwrites dead sQ/sK; residual added in LN1) ----
    {
      short8 cf[3][4];
#pragma unroll
      for (int mt = 0; mt < 3; ++mt)
#pragma unroll
        for (int ks = 0; ks < 4; ++ks)
          cf[mt][ks] = *(const short8*)(sA + (mt * 16 + l15) * LDA + ks * 32 + quad * 8);
      const unsigned short* wbase = ws + WO_OFF + lay * PL_QKVO;
      for (int u = wid; u < 7; u += 4) {
        short8 wf[4];
        ldwf4(wbase + (size_t)u * 2048 + (size_t)lane * 8, wf);
        const int n0 = u * 16 + quad * 4;
        floatx4 bias = {0.f, 0.f, 0.f, 0.f};
        if (n0 < D) bias = *(const floatx4*)(bo + lay * D + n0);
        floatx4 a0 = bias, a1 = bias, a2 = bias;
#pragma unroll
        for (int ks = 0; ks < 4; ++ks) {
          a0 = __builtin_amdgcn_mfma_f32_16x16x32_bf16(wf[ks], cf[0][ks], a0, 0, 0, 0);
          a1 = __builtin_amdgcn_mfma_f32_16x16x32_bf16(wf[ks], cf[1][ks], a1, 0, 0, 0);
          a2 = __builtin_amdgcn_mfma_f32_16x16x32_bf16(wf[ks], cf[2][ks], a2, 0, 0, 0);
        }
        if (n0 < D) {
          const floatx4 av[3] = {a0, a1, a2};
#pragma unroll
          for (int mt = 0; mt < 3; ++mt)
            *(floatx4*)(scr + (mt * 16 + l15) * D + n0) = av[mt];
        }
      }
    }
    __syncthreads();
    if (tid < 192)
      ln_rows(sXf + row_o * D, scr + row_o * D, g1 + lay * D, bt1 + lay * D,
              sA + row_o * LDA, ln_o, cnt_o);
    __syncthreads();

    // ---- FFN: 3 chunks {192,192,128}; sH overwrites dead scr ----
    {
      short8 ff[3][4];
#pragma unroll
      for (int mt = 0; mt < 3; ++mt)
#pragma unroll
        for (int ks = 0; ks < 4; ++ks)
          ff[mt][ks] = *(const short8*)(sA + (mt * 16 + l15) * LDA + ks * 32 + quad * 8);
      floatx4 facc[2][3];
      const int ntA = wid, ntB = wid + 4;  // FFN2 output tiles (ntB if < 7)
#pragma unroll
      for (int idx = 0; idx < 2; ++idx) {
        const int nt = idx == 0 ? ntA : ntB;
        const int n0 = nt * 16 + quad * 4;
        floatx4 bias = {0.f, 0.f, 0.f, 0.f};
        if (nt < 7 && n0 < D) bias = *(const floatx4*)(b2 + lay * D + n0);
#pragma unroll
        for (int mt = 0; mt < 3; ++mt) facc[idx][mt] = bias;
      }
      const unsigned short* w1b = ws + W1_OFF + (size_t)lay * PL_W1;
      const unsigned short* w2b = ws + W2_OFF + (size_t)lay * PL_W2;

#pragma unroll
      for (int c = 0; c < 3; ++c) {
        const int base_nt = c * 12;               // chunk hidden base / 16
        const int cnt_nt = (c == 2) ? 8 : 12;     // hidden tiles this chunk
        const int kb = c * 6, ke = kb + ((c == 2) ? 4 : 6);  // FFN2 ks range
        // FFN1: 2-3 units per wave
        for (int l = wid; l < cnt_nt; l += 4) {
          const int ntg = base_nt + l;
          short8 wf[4];
          ldwf4(w1b + (size_t)ntg * 2048 + (size_t)lane * 8, wf);
          const floatx4 b1v = *(const floatx4*)(b1 + lay * FF + ntg * 16 + quad * 4);
          floatx4 a0 = b1v, a1 = b1v, a2 = b1v;
#pragma unroll
          for (int ks = 0; ks < 4; ++ks) {
            a0 = __builtin_amdgcn_mfma_f32_16x16x32_bf16(wf[ks], ff[0][ks], a0, 0, 0, 0);
            a1 = __builtin_amdgcn_mfma_f32_16x16x32_bf16(wf[ks], ff[1][ks], a1, 0, 0, 0);
            a2 = __builtin_amdgcn_mfma_f32_16x16x32_bf16(wf[ks], ff[2][ks], a2, 0, 0, 0);
          }
          const int nloc = l * 16 + quad * 4;
          const floatx4 av[3] = {a0, a1, a2};
#pragma unroll
          for (int mt = 0; mt < 3; ++mt) {
            const int row = mt * 16 + l15;
            floatx4 r;
            r.x = fmaxf(av[mt].x, 0.f); r.y = fmaxf(av[mt].y, 0.f);
            r.z = fmaxf(av[mt].z, 0.f); r.w = fmaxf(av[mt].w, 0.f);
            st_bf4(sH + row * LDH + nloc, r);
          }
        }
        __syncthreads();
        // FFN2: wave's 1-2 nt units share hf reads; rolling wf pair prefetch
        short8 wA = *(const short8*)(w2b + (size_t)(ntA * 16 + kb) * 512 + (size_t)lane * 8);
        short8 wB = wA;
        if (ntB < 7)
          wB = *(const short8*)(w2b + (size_t)(ntB * 16 + kb) * 512 + (size_t)lane * 8);
        for (int ksl = kb; ksl < ke; ++ksl) {
          short8 nA = wA, nB = wB;
          if (ksl + 1 < ke) {
            nA = *(const short8*)(w2b + (size_t)(ntA * 16 + ksl + 1) * 512 + (size_t)lane * 8);
            if (ntB < 7)
              nB = *(const short8*)(w2b + (size_t)(ntB * 16 + ksl + 1) * 512 + (size_t)lane * 8);
          }
          short8 hf[3];
#pragma unroll
          for (int mt = 0; mt < 3; ++mt)
            hf[mt] = *(const short8*)(sH + (mt * 16 + l15) * LDH + (ksl - kb) * 32 + quad * 8);
#pragma unroll
          for (int mt = 0; mt < 3; ++mt)
            facc[0][mt] = __builtin_amdgcn_mfma_f32_16x16x32_bf16(wA, hf[mt], facc[0][mt], 0, 0, 0);
          if (ntB < 7) {
#pragma unroll
            for (int mt = 0; mt < 3; ++mt)
              facc[1][mt] = __builtin_amdgcn_mfma_f32_16x16x32_bf16(wB, hf[mt], facc[1][mt], 0, 0, 0);
          }
          wA = nA; wB = nB;
        }
        __syncthreads();  // sH consumed; next FFN1 / scr write safe
      }
      // FFN2 epilogue -> scr (overwrites dead sH)
#pragma unroll
      for (int idx = 0; idx < 2; ++idx) {
        const int nt = idx == 0 ? ntA : ntB;
        const int n0 = nt * 16 + quad * 4;
        if (nt < 7 && n0 < D) {
#pragma unroll
          for (int mt = 0; mt < 3; ++mt)
            *(floatx4*)(scr + (mt * 16 + l15) * D + n0) = facc[idx][mt];
        }
      }
    }
    __syncthreads();
    if (tid < 192)
      ln_rows(sXf + row_o * D, scr + row_o * D, g2 + lay * D, bt2 + lay * D,
              sA + row_o * LDA, ln_o, cnt_o);
    __syncthreads();
  }

  // ---- classifier (fp32 VALU, exact): reads sXf master directly ----
  if (tid < 160) {
    const int c = tid % 40, eg = tid / 40;
    float acc[4];
#pragma unroll
    for (int i = 0; i < 4; ++i) acc[i] = bfc[c];
    const floatx4* wr = (const floatx4*)(Wf + c * 300);
    for (int kq = 0; kq < 75; ++kq) {
      const floatx4 w4 = wr[kq];
#pragma unroll
      for (int i = 0; i < 4; ++i) {
        const floatx4 x4 = *(const floatx4*)(sXf + (eg * 4 + i) * 300 + kq * 4);
        acc[i] += w4.x * x4.x + w4.y * x4.y + w4.z * x4.z + w4.w * x4.w;
      }
    }
#pragma unroll
    for (int i = 0; i < 4; ++i)
      gout[((size_t)blk * NB + eg * 4 + i) * CLS + c] = acc[i];
  }
}

extern "C" void kernel_launch(void* const* d_in, const int* in_sizes, int n_in,
                              void* d_out, int out_size, void* d_ws,
                              size_t ws_size, hipStream_t stream) {
  const float* x   = (const float*)d_in[0];
  const float* We  = (const float*)d_in[3];
  const float* be  = (const float*)d_in[4];
  const float* pe  = (const float*)d_in[5];
  const float* Wq  = (const float*)d_in[6];
  const float* bq  = (const float*)d_in[7];
  const float* Wk  = (const float*)d_in[8];
  const float* bk  = (const float*)d_in[9];
  const float* Wv  = (const float*)d_in[10];
  const float* bv  = (const float*)d_in[11];
  const float* Wo  = (const float*)d_in[12];
  const float* bo  = (const float*)d_in[13];
  const float* g1  = (const float*)d_in[14];
  const float* bt1 = (const float*)d_in[15];
  const float* W1  = (const float*)d_in[16];
  const float* b1  = (const float*)d_in[17];
  const float* W2  = (const float*)d_in[18];
  const float* b2  = (const float*)d_in[19];
  const float* g2  = (const float*)d_in[20];
  const float* bt2 = (const float*)d_in[21];
  const float* Wf  = (const float*)d_in[22];
  const float* bf  = (const float*)d_in[23];
  float* out = (float*)d_out;
  unsigned short* ws = (unsigned short*)d_ws;

  prep_weights<<<710, 256, 0, stream>>>(Wq, Wk, Wv, Wo, W1, W2, We, ws);

  const int B = in_sizes[0] / (S * DIN);
  const int blocks = B / NB;  // 4096
  geomap_mfma<<<blocks, 256, 0, stream>>>(x, be, pe, bq, bk, bv, bo,
                                          g1, bt1, b1, b2, g2, bt2, Wf, bf,
                                          ws, out);
}